// Round 11
// baseline (115.360 us; speedup 1.0000x reference)
//
#include <hip/hip_runtime.h>
#include <hip/hip_bf16.h>
#include <stdint.h>

#define B_SZ 4096
#define F_N 16
#define V_SZ 20000
#define E_SZ 64
#define HID 1024

typedef __attribute__((ext_vector_type(8))) _Float16 f16x8;
typedef __attribute__((ext_vector_type(4))) _Float16 f16x4;
typedef __attribute__((ext_vector_type(4))) float f32x4;

__device__ __forceinline__ void gload16(const void* g, void* l) {
  __builtin_amdgcn_global_load_lds(
      (const __attribute__((address_space(1))) void*)g,
      (__attribute__((address_space(3))) void*)l, 16, 0, 0);
}

// s3(r): spreads a 128B-stride row-major LDS tile across the 8 16B bank
// groups (2-lane/bank floor for wave64 = free). s3(r+64) == s3(r).
__device__ __forceinline__ int s3(int r) { return (r ^ (r >> 3)) & 7; }

// ---------------------------------------------------------------------------
// prep: blocks [0,2048) convert+transpose weights (wt[z][n][k] = f16 w_z[k][n]);
//       blocks [2048,6144) gather embeddings straight to f16.
//       block 2048 also resets the 96 inter-layer sync flags.
// ---------------------------------------------------------------------------
__global__ __launch_bounds__(256) void prep(
    const int* __restrict__ idx, const float* __restrict__ emb,
    const float* __restrict__ w0, const float* __restrict__ w1,
    const float* __restrict__ w2, const float* __restrict__ w3,
    _Float16* __restrict__ wt, _Float16* __restrict__ xw,
    int* __restrict__ flags) {
  const int cb = blockIdx.x;
  const int t = threadIdx.x;
  if (cb < 2048) {
    const int z = cb >> 9, rem = cb & 511;
    const float* w = (z == 0) ? w0 : (z == 1) ? w1 : (z == 2) ? w2 : w3;
    _Float16* outp = wt + (size_t)z * HID * HID;
    __shared__ float tile[64][33];
    const int k0 = (rem >> 5) * 64, n0 = (rem & 31) * 32;
    const int c = t & 31;
#pragma unroll
    for (int q = 0; q < 8; ++q) {
      int r = (t >> 5) + q * 8;  // k-row within tile
      tile[r][c] = w[(size_t)(k0 + r) * HID + n0 + c];
    }
    __syncthreads();
#pragma unroll
    for (int q = 0; q < 4; ++q) {
      int s = t + q * 256;  // 0..1023
      int n = s >> 5, c2 = s & 31;
      union { _Float16 h[2]; uint32_t u; } p;
      p.h[0] = (_Float16)tile[2 * c2][n];
      p.h[1] = (_Float16)tile[2 * c2 + 1][n];
      *(uint32_t*)(outp + (size_t)(n0 + n) * HID + k0 + 2 * c2) = p.u;
    }
  } else {
    if (cb == 2048 && t < 96) flags[t] = 0;  // reset sync flags (pre-gemm)
    int i = (cb - 2048) * 256 + t;  // f4 index in [0, B*256)
    int b = i >> 8;
    int r = i & 255;
    int f = r >> 4;
    int e4 = r & 15;
    int id = idx[b * F_N + f];
    float4 v = *(const float4*)(emb + ((size_t)f * V_SZ + id) * E_SZ + e4 * 4);
    f16x4 h = {(_Float16)v.x, (_Float16)v.y, (_Float16)v.z, (_Float16)v.w};
    *(f16x4*)(xw + (size_t)b * HID + r * 4) = h;
  }
}

// ---------------------------------------------------------------------------
// All 4 layers fused into one persistent kernel. Grid 256 = 1 block/CU
// (64 KB LDS, 512 thr -> all blocks co-resident; spin-sync is deadlock-free).
// Per layer: r6-champion K-loop (128x128 tile, BK=64, 8 waves 2Mx2Nx2K,
// 2 LDS buffers, depth-1 prefetch, counted vmcnt, 2 barriers/iter,
// pre-swizzled source chunk + linear dest + swizzled read), OPERAND-SWAPPED
// MFMA (r10-verified): lane holds row=lr, 4 consecutive cols -> f16x4
// 8B C-stores + float4 bias loads. wk-pair reduction through LDS.
// Inter-layer dependency: block (bm,bn) at layer L+1 reads A rows
// bm..bm+127 = outputs of the 8 blocks sharing bm ("panel"). Sync:
// producer __syncthreads (drains stores: vmcnt(0) before s_barrier) ->
// release atomicAdd(flags[L][panel]); consumer t0 spins on agent-scope
// acquire load (L1-inv) until ==8. Each layer writes a distinct buffer,
// so no stale-L1 lines exist regardless.
// XCD swizzle: XCD k (= bid%8) owns row-panels 4k..4k+3 (L2 locality;
// correctness does not depend on it).
// ---------------------------------------------------------------------------
__global__ __launch_bounds__(512) void gemm4_fused(
    const _Float16* __restrict__ xw, const _Float16* __restrict__ wt,
    const float* __restrict__ b0, const float* __restrict__ b1,
    const float* __restrict__ b2, const float* __restrict__ b3,
    _Float16* __restrict__ cat, _Float16* __restrict__ lf,
    int* __restrict__ flags) {
  __shared__ __align__(16) char shraw[65536];
#define AS(b) ((_Float16*)(shraw + (b) * 32768))
#define BS(b) ((_Float16*)(shraw + (b) * 32768 + 16384))

  const int t = threadIdx.x;
  const int l = ((blockIdx.x & 7) << 5) | (blockIdx.x >> 3);
  const int bm = (l >> 3) * 128, bn = (l & 7) * 128;
  const int panel = l >> 3;

  const int w = t >> 6, lane = t & 63;
  const int wk = w & 1, wn = (w >> 1) & 1, wm = w >> 2;
  const int lr = lane & 15, lg = lane >> 4;

  const size_t RB = (size_t)B_SZ * HID;
  const size_t WSZ = (size_t)HID * HID;

  // staging map (constant across layers)
  const int srow = t >> 3, cdst = t & 7;
  const int csrc = cdst ^ s3(srow);
  const int ld0 = t * 8, ld1 = t * 8 + 4096;  // halves, linear dest

  // frag read offsets (halves): wave reads k-chunks wk*4+lg
  int aoff[4], boff[4];
#pragma unroll
  for (int i = 0; i < 4; i++) {
    int ra = wm * 64 + i * 16 + lr;
    aoff[i] = ra * 64 + (((wk * 4 + lg) ^ s3(ra)) * 8);
    int rb = wn * 64 + i * 16 + lr;
    boff[i] = rb * 64 + (((wk * 4 + lg) ^ s3(rb)) * 8);
  }

#define STAGE(buf, ko)                                   \
  gload16(ga0 + (ko), &AS(buf)[ld0]);                    \
  gload16(ga0 + (ko) + (size_t)64 * HID, &AS(buf)[ld1]); \
  gload16(gb0 + (ko), &BS(buf)[ld0]);                    \
  gload16(gb0 + (ko) + (size_t)64 * HID, &BS(buf)[ld1]);

  for (int L = 0; L < 4; ++L) {
    const _Float16* A = (L == 0) ? xw : cat + (size_t)(L - 1) * RB;
    _Float16* C = (L == 3) ? lf : cat + (size_t)L * RB;
    const float* bias = (L == 0) ? b0 : (L == 1) ? b1 : (L == 2) ? b2 : b3;
    const _Float16* Wt = wt + (size_t)L * WSZ;

    if (L > 0) {
      // wait until all 8 producers of this row-panel have published layer L-1
      if (t == 0) {
        while (__hip_atomic_load(&flags[(L - 1) * 32 + panel],
                                 __ATOMIC_ACQUIRE,
                                 __HIP_MEMORY_SCOPE_AGENT) < 8)
          __builtin_amdgcn_s_sleep(2);
      }
      __syncthreads();
    }

    const _Float16* ga0 = A + (size_t)(bm + srow) * HID + csrc * 8;
    const _Float16* gb0 = Wt + (size_t)(bn + srow) * HID + csrc * 8;

    f32x4 acc[4][4] = {};

    STAGE(0, 0)  // tile 0

    for (int tI = 0; tI < 16; ++tI) {
      const int cur = tI & 1;
      if (tI < 15) {
        STAGE(cur ^ 1, (tI + 1) * 64)  // prefetch next tile
      }
      if (tI < 15)
        asm volatile("s_waitcnt vmcnt(4)" ::: "memory");  // tile tI landed
      else
        asm volatile("s_waitcnt vmcnt(0)" ::: "memory");
      asm volatile("s_barrier" ::: "memory");

      f16x8 a[4], b[4];
#pragma unroll
      for (int mi = 0; mi < 4; mi++) a[mi] = *(const f16x8*)&AS(cur)[aoff[mi]];
#pragma unroll
      for (int ni = 0; ni < 4; ni++) b[ni] = *(const f16x8*)&BS(cur)[boff[ni]];
#pragma unroll
      for (int mi = 0; mi < 4; mi++)
#pragma unroll
        for (int ni = 0; ni < 4; ni++)
          acc[mi][ni] = __builtin_amdgcn_mfma_f32_16x16x32_f16(
              b[ni], a[mi], acc[mi][ni], 0, 0, 0);  // SWAPPED operands

      asm volatile("s_barrier" ::: "memory");  // guard buffer overwrite
    }

    // Swapped-D layout: acc[mi][ni][j] = Csub[wm*64+mi*16+lr][wn*64+ni*16+lg*4+j]
    // wk-pair reduction through LDS (aliases staging buffers):
    // addr = u*64 + ((vb^lr)<<2)+j, u=mi*16+lr, vb=ni*4+lg.
    float* red = (float*)shraw;
    float* R = red + ((wm << 1) | wn) * 4096;
    if (wk == 1) {
#pragma unroll
      for (int mi = 0; mi < 4; mi++)
#pragma unroll
        for (int ni = 0; ni < 4; ni++) {
          int u = mi * 16 + lr;
          int vb = ni * 4 + lg;
          *(f32x4*)&R[u * 64 + ((vb ^ lr) << 2)] = acc[mi][ni];
        }
    }
    asm volatile("s_barrier" ::: "memory");
    if (wk == 0) {
#pragma unroll
      for (int mi = 0; mi < 4; mi++)
#pragma unroll
        for (int ni = 0; ni < 4; ni++) {
          int u = mi * 16 + lr;
          int vb = ni * 4 + lg;
          f32x4 p = *(const f32x4*)&R[u * 64 + ((vb ^ lr) << 2)];
          acc[mi][ni] += p;
        }
      // epilogue: per (mi,ni) one f16x4 (8B) store of 4 consecutive cols
#pragma unroll
      for (int ni = 0; ni < 4; ni++) {
        int colb = bn + wn * 64 + ni * 16 + lg * 4;
        float4 bv = *(const float4*)&bias[colb];
#pragma unroll
        for (int mi = 0; mi < 4; mi++) {
          int row = bm + wm * 64 + mi * 16 + lr;
          f16x4 hv;
          float x0 = acc[mi][ni][0] + bv.x;
          float x1 = acc[mi][ni][1] + bv.y;
          float x2 = acc[mi][ni][2] + bv.z;
          float x3 = acc[mi][ni][3] + bv.w;
          hv[0] = (_Float16)(x0 > 0.f ? x0 : 0.f);
          hv[1] = (_Float16)(x1 > 0.f ? x1 : 0.f);
          hv[2] = (_Float16)(x2 > 0.f ? x2 : 0.f);
          hv[3] = (_Float16)(x3 > 0.f ? x3 : 0.f);
          *(f16x4*)&C[(size_t)row * HID + colb] = hv;
        }
      }
    }

    // publish this block's slice of layer L (drain stores first), and order
    // reduction-LDS reads before next layer's STAGE overwrites shraw.
    __syncthreads();  // emits s_waitcnt vmcnt(0) lgkmcnt(0) before s_barrier
    if (L < 3 && t == 0) {
      __threadfence();
      __hip_atomic_fetch_add(&flags[L * 32 + panel], 1, __ATOMIC_RELEASE,
                             __HIP_MEMORY_SCOPE_AGENT);
    }
  }
#undef STAGE
#undef AS
#undef BS
}

// ---------------------------------------------------------------------------
// Attention-over-layers + final dot; reads f16 activations, fp32 math.
// Hm[b,j] = cat[3b+j] with cat = [l0; l1; l2] row-stacked.
// ---------------------------------------------------------------------------
__global__ __launch_bounds__(256) void attn_final(
    const _Float16* __restrict__ cat, const _Float16* __restrict__ lf,
    const float* __restrict__ wf, const float* __restrict__ bfin,
    float* __restrict__ out) {
  const int wave = threadIdx.x >> 6;
  const int lane = threadIdx.x & 63;
  const int b = blockIdx.x * 4 + wave;

  const _Float16* h0 = cat + (size_t)(3 * b + 0) * 1024;
  const _Float16* h1 = cat + (size_t)(3 * b + 1) * 1024;
  const _Float16* h2 = cat + (size_t)(3 * b + 2) * 1024;
  const _Float16* lfr = lf + (size_t)b * 1024;

  float s01 = 0.f, s02 = 0.f, s12 = 0.f;
  float d0 = 0.f, d1 = 0.f, d2 = 0.f, dl = 0.f;

#pragma unroll
  for (int q = 0; q < 2; ++q) {
    int e8 = (lane + q * 64) * 8;
    f16x8 a0 = *(const f16x8*)(h0 + e8);
    f16x8 a1 = *(const f16x8*)(h1 + e8);
    f16x8 a2 = *(const f16x8*)(h2 + e8);
    f16x8 al = *(const f16x8*)(lfr + e8);
    float4 u0a = *(const float4*)(wf + e8);
    float4 u0b = *(const float4*)(wf + e8 + 4);
    float4 u1a = *(const float4*)(wf + 1024 + e8);
    float4 u1b = *(const float4*)(wf + 1024 + e8 + 4);
    float wf0[8] = {u0a.x, u0a.y, u0a.z, u0a.w, u0b.x, u0b.y, u0b.z, u0b.w};
    float wf1[8] = {u1a.x, u1a.y, u1a.z, u1a.w, u1b.x, u1b.y, u1b.z, u1b.w};
#pragma unroll
    for (int j = 0; j < 8; ++j) {
      float p0 = (float)a0[j], p1 = (float)a1[j], p2 = (float)a2[j];
      float pl = (float)al[j];
      s01 = fmaf(p0, p1, s01);
      s02 = fmaf(p0, p2, s02);
      s12 = fmaf(p1, p2, s12);
      d0 = fmaf(p0, wf1[j], d0);
      d1 = fmaf(p1, wf1[j], d1);
      d2 = fmaf(p2, wf1[j], d2);
      dl = fmaf(pl, wf0[j], dl);
    }
  }

#pragma unroll
  for (int m = 1; m < 64; m <<= 1) {
    s01 += __shfl_xor(s01, m);
    s02 += __shfl_xor(s02, m);
    s12 += __shfl_xor(s12, m);
    d0 += __shfl_xor(d0, m);
    d1 += __shfl_xor(d1, m);
    d2 += __shfl_xor(d2, m);
    dl += __shfl_xor(dl, m);
  }

  if (lane == 0) {
    float c0 = 0.f, c1 = 0.f, c2 = 0.f;
    {
      float m = fmaxf(0.f, fmaxf(s01, s02));
      float e0 = expf(0.f - m), e1 = expf(s01 - m), e2 = expf(s02 - m);
      float inv = 1.f / (e0 + e1 + e2);
      c0 += e0 * inv; c1 += e1 * inv; c2 += e2 * inv;
    }
    {
      float m = fmaxf(s01, fmaxf(0.f, s12));
      float e0 = expf(s01 - m), e1 = expf(0.f - m), e2 = expf(s12 - m);
      float inv = 1.f / (e0 + e1 + e2);
      c0 += e0 * inv; c1 += e1 * inv; c2 += e2 * inv;
    }
    {
      float m = fmaxf(s02, fmaxf(s12, 0.f));
      float e0 = expf(s02 - m), e1 = expf(s12 - m), e2 = expf(0.f - m);
      float inv = 1.f / (e0 + e1 + e2);
      c0 += e0 * inv; c1 += e1 * inv; c2 += e2 * inv;
    }
    out[b] = dl + c0 * d0 + c1 * d1 + c2 * d2 + bfin[0];
  }
}

// ---------------------------------------------------------------------------
extern "C" void kernel_launch(void* const* d_in, const int* in_sizes, int n_in,
                              void* d_out, int out_size, void* d_ws,
                              size_t ws_size, hipStream_t stream) {
  const int* idx = (const int*)d_in[0];
  const float* emb = (const float*)d_in[1];
  const float* w0 = (const float*)d_in[2];
  const float* b0 = (const float*)d_in[3];
  const float* w1 = (const float*)d_in[4];
  const float* b1 = (const float*)d_in[5];
  const float* w2 = (const float*)d_in[6];
  const float* b2 = (const float*)d_in[7];
  const float* w3 = (const float*)d_in[8];
  const float* b3 = (const float*)d_in[9];
  const float* wf = (const float*)d_in[10];
  const float* bfin = (const float*)d_in[11];
  float* out = (float*)d_out;

  const size_t RB = (size_t)B_SZ * HID;  // 4M elements
  const size_t WSZ = (size_t)HID * HID;  // 1M elements

  _Float16* wt = (_Float16*)d_ws;   // [4][1024][1024]  8 MB
  _Float16* xw16 = wt + 4 * WSZ;    // [B,1024]         8 MB
  _Float16* cat16 = xw16 + RB;      // [3B,1024]       24 MB
  _Float16* lf16 = cat16 + 3 * RB;  // [B,1024]         8 MB
  int* flags = (int*)(lf16 + RB);   // [3][32] sync counters

  prep<<<6144, 256, 0, stream>>>(idx, emb, w0, w1, w2, w3, wt, xw16, flags);

  gemm4_fused<<<256, 512, 0, stream>>>(xw16, wt, b0, b1, b2, b3, cat16, lf16,
                                       flags);

  attn_final<<<B_SZ / 4, 256, 0, stream>>>(cat16, lf16, wf, bfin, out);
}

// Round 12
// 75.836 us; speedup vs baseline: 1.5212x; 1.5212x over previous
//
#include <hip/hip_runtime.h>
#include <hip/hip_bf16.h>
#include <stdint.h>

#define B_SZ 4096
#define F_N 16
#define V_SZ 20000
#define E_SZ 64
#define HID 1024

typedef __attribute__((ext_vector_type(8))) _Float16 f16x8;
typedef __attribute__((ext_vector_type(4))) _Float16 f16x4;
typedef __attribute__((ext_vector_type(4))) float f32x4;

__device__ __forceinline__ void gload16(const void* g, void* l) {
  __builtin_amdgcn_global_load_lds(
      (const __attribute__((address_space(1))) void*)g,
      (__attribute__((address_space(3))) void*)l, 16, 0, 0);
}

// s3(r): spreads a 128B-stride row-major LDS tile across the 8 16B bank
// groups (counter-verified: ~1 conflict-cycle per ds_read_b128, near-floor).
// s3(r+64) == s3(r).
__device__ __forceinline__ int s3(int r) { return (r ^ (r >> 3)) & 7; }

// ---------------------------------------------------------------------------
// prep: blocks [0,2048) convert+transpose weights (wt[z][n][k] = f16 w_z[k][n]);
//       blocks [2048,6144) gather embeddings straight to f16.
// ---------------------------------------------------------------------------
__global__ __launch_bounds__(256) void prep(
    const int* __restrict__ idx, const float* __restrict__ emb,
    const float* __restrict__ w0, const float* __restrict__ w1,
    const float* __restrict__ w2, const float* __restrict__ w3,
    _Float16* __restrict__ wt, _Float16* __restrict__ xw) {
  const int cb = blockIdx.x;
  const int t = threadIdx.x;
  if (cb < 2048) {
    const int z = cb >> 9, rem = cb & 511;
    const float* w = (z == 0) ? w0 : (z == 1) ? w1 : (z == 2) ? w2 : w3;
    _Float16* outp = wt + (size_t)z * HID * HID;
    __shared__ float tile[64][33];
    const int k0 = (rem >> 5) * 64, n0 = (rem & 31) * 32;
    const int c = t & 31;
#pragma unroll
    for (int q = 0; q < 8; ++q) {
      int r = (t >> 5) + q * 8;  // k-row within tile
      tile[r][c] = w[(size_t)(k0 + r) * HID + n0 + c];
    }
    __syncthreads();
#pragma unroll
    for (int q = 0; q < 4; ++q) {
      int s = t + q * 256;  // 0..1023
      int n = s >> 5, c2 = s & 31;
      union { _Float16 h[2]; uint32_t u; } p;
      p.h[0] = (_Float16)tile[2 * c2][n];
      p.h[1] = (_Float16)tile[2 * c2 + 1][n];
      *(uint32_t*)(outp + (size_t)(n0 + n) * HID + k0 + 2 * c2) = p.u;
    }
  } else {
    int i = (cb - 2048) * 256 + t;  // f4 index in [0, B*256)
    int b = i >> 8;
    int r = i & 255;
    int f = r >> 4;
    int e4 = r & 15;
    int id = idx[b * F_N + f];
    float4 v = *(const float4*)(emb + ((size_t)f * V_SZ + id) * E_SZ + e4 * 4);
    f16x4 h = {(_Float16)v.x, (_Float16)v.y, (_Float16)v.z, (_Float16)v.w};
    *(f16x4*)(xw + (size_t)b * HID + r * 4) = h;
  }
}

// ---------------------------------------------------------------------------
// C = relu(A @ Wt^T + bias) -> f16.  MFMA 16x16x32_f16, OPERAND-SWAPPED
// (r10/r11-verified): acc = mfma(b_frag, a_frag, acc) so each lane's D
// holds ONE row x 4 consecutive cols -> f16x4 (8B) C-stores + float4 bias.
// K-loop = r6 champion: 128x128 tile, BK=64, 8 waves 2M x 2N x 2K (64x64
// quadrant, half-K per wave), 2 LDS buffers (64 KB), depth-1 prefetch,
// counted vmcnt, 2 barriers/iter, pre-swizzled source chunk + linear LDS
// dest + swizzled read. wk-pairs reduce partials through LDS at the end.
// XCD swizzle: XCD k (= bid%8) owns row-panels 4k..4k+3 (keeps each
// layer's 2 MB weights + 1 MB A-panels L2-resident per XCD; separate
// launches keep all CUs on ONE layer -> no cross-layer L2 thrash, which
// is what killed the r11 fusion).
// ---------------------------------------------------------------------------
__global__ __launch_bounds__(512) void gemm_mfma(
    const _Float16* __restrict__ A, const _Float16* __restrict__ Wt,
    const float* __restrict__ bias, _Float16* __restrict__ C) {
  __shared__ __align__(16) char shraw[65536];
#define AS(b) ((_Float16*)(shraw + (b) * 32768))
#define BS(b) ((_Float16*)(shraw + (b) * 32768 + 16384))

  const int t = threadIdx.x;
  const int l = ((blockIdx.x & 7) << 5) | (blockIdx.x >> 3);
  const int bm = (l >> 3) * 128, bn = (l & 7) * 128;

  const int w = t >> 6, lane = t & 63;
  const int wk = w & 1, wn = (w >> 1) & 1, wm = w >> 2;
  const int lr = lane & 15, lg = lane >> 4;

  // --- staging: slots s in [0,1024): row=s>>3, chunk=s&7 (16B units).
  // thread t owns slots {t, t+512} of each matrix; s3(srow)==s3(srow+64).
  const int srow = t >> 3, cdst = t & 7;
  const int csrc = cdst ^ s3(srow);
  const _Float16* ga0 = A + (size_t)(bm + srow) * HID + csrc * 8;
  const _Float16* gb0 = Wt + (size_t)(bn + srow) * HID + csrc * 8;
  const int ld0 = t * 8, ld1 = t * 8 + 4096;  // halves, linear dest

  // --- frag read offsets (halves): wave reads k-chunks wk*4+lg (k=wk*32..)
  int aoff[4], boff[4];
#pragma unroll
  for (int i = 0; i < 4; i++) {
    int ra = wm * 64 + i * 16 + lr;
    aoff[i] = ra * 64 + (((wk * 4 + lg) ^ s3(ra)) * 8);
    int rb = wn * 64 + i * 16 + lr;
    boff[i] = rb * 64 + (((wk * 4 + lg) ^ s3(rb)) * 8);
  }

  f32x4 acc[4][4] = {};

#define STAGE(buf, ko)                                   \
  gload16(ga0 + (ko), &AS(buf)[ld0]);                    \
  gload16(ga0 + (ko) + (size_t)64 * HID, &AS(buf)[ld1]); \
  gload16(gb0 + (ko), &BS(buf)[ld0]);                    \
  gload16(gb0 + (ko) + (size_t)64 * HID, &BS(buf)[ld1]);

  STAGE(0, 0)  // tile 0

  for (int tI = 0; tI < 16; ++tI) {
    const int cur = tI & 1;
    if (tI < 15) {
      STAGE(cur ^ 1, (tI + 1) * 64)  // prefetch next tile (4 loads/thread)
    }
    if (tI < 15)
      asm volatile("s_waitcnt vmcnt(4)" ::: "memory");  // tile tI landed
    else
      asm volatile("s_waitcnt vmcnt(0)" ::: "memory");
    asm volatile("s_barrier" ::: "memory");

    f16x8 a[4], b[4];
#pragma unroll
    for (int mi = 0; mi < 4; mi++) a[mi] = *(const f16x8*)&AS(cur)[aoff[mi]];
#pragma unroll
    for (int ni = 0; ni < 4; ni++) b[ni] = *(const f16x8*)&BS(cur)[boff[ni]];
#pragma unroll
    for (int mi = 0; mi < 4; mi++)
#pragma unroll
      for (int ni = 0; ni < 4; ni++)
        acc[mi][ni] = __builtin_amdgcn_mfma_f32_16x16x32_f16(
            b[ni], a[mi], acc[mi][ni], 0, 0, 0);  // SWAPPED operands

    asm volatile("s_barrier" ::: "memory");  // guard buffer overwrite
  }
#undef STAGE

  // --- Swapped-D layout: acc[mi][ni][j] =
  //     Csub[row = wm*64+mi*16+lr][col = wn*64+ni*16+lg*4+j]
  // wk-pair reduction through LDS (aliases the staging buffers, 64 KB):
  // addr = u*64 + ((vb^lr)<<2)+j, u=mi*16+lr (row), vb=ni*4+lg (col-chunk);
  // XOR keeps b128 writes/reads spread across bank groups.
  float* red = (float*)shraw;
  float* R = red + ((wm << 1) | wn) * 4096;
  if (wk == 1) {
#pragma unroll
    for (int mi = 0; mi < 4; mi++)
#pragma unroll
      for (int ni = 0; ni < 4; ni++) {
        int u = mi * 16 + lr;
        int vb = ni * 4 + lg;
        *(f32x4*)&R[u * 64 + ((vb ^ lr) << 2)] = acc[mi][ni];
      }
  }
  asm volatile("s_barrier" ::: "memory");
  if (wk == 0) {
#pragma unroll
    for (int mi = 0; mi < 4; mi++)
#pragma unroll
      for (int ni = 0; ni < 4; ni++) {
        int u = mi * 16 + lr;
        int vb = ni * 4 + lg;
        f32x4 p = *(const f32x4*)&R[u * 64 + ((vb ^ lr) << 2)];
        acc[mi][ni] += p;
      }
    // epilogue: per (mi,ni) one f16x4 (8B) store of 4 consecutive cols
#pragma unroll
    for (int ni = 0; ni < 4; ni++) {
      int colb = bn + wn * 64 + ni * 16 + lg * 4;
      float4 bv = *(const float4*)&bias[colb];
#pragma unroll
      for (int mi = 0; mi < 4; mi++) {
        int row = bm + wm * 64 + mi * 16 + lr;
        f16x4 hv;
        float x0 = acc[mi][ni][0] + bv.x;
        float x1 = acc[mi][ni][1] + bv.y;
        float x2 = acc[mi][ni][2] + bv.z;
        float x3 = acc[mi][ni][3] + bv.w;
        hv[0] = (_Float16)(x0 > 0.f ? x0 : 0.f);
        hv[1] = (_Float16)(x1 > 0.f ? x1 : 0.f);
        hv[2] = (_Float16)(x2 > 0.f ? x2 : 0.f);
        hv[3] = (_Float16)(x3 > 0.f ? x3 : 0.f);
        *(f16x4*)&C[(size_t)row * HID + colb] = hv;
      }
    }
  }
#undef AS
#undef BS
}

// ---------------------------------------------------------------------------
// Attention-over-layers + final dot; reads f16 activations, fp32 math.
// Hm[b,j] = cat[3b+j] with cat = [l0; l1; l2] row-stacked.
// ---------------------------------------------------------------------------
__global__ __launch_bounds__(256) void attn_final(
    const _Float16* __restrict__ cat, const _Float16* __restrict__ lf,
    const float* __restrict__ wf, const float* __restrict__ bfin,
    float* __restrict__ out) {
  const int wave = threadIdx.x >> 6;
  const int lane = threadIdx.x & 63;
  const int b = blockIdx.x * 4 + wave;

  const _Float16* h0 = cat + (size_t)(3 * b + 0) * 1024;
  const _Float16* h1 = cat + (size_t)(3 * b + 1) * 1024;
  const _Float16* h2 = cat + (size_t)(3 * b + 2) * 1024;
  const _Float16* lfr = lf + (size_t)b * 1024;

  float s01 = 0.f, s02 = 0.f, s12 = 0.f;
  float d0 = 0.f, d1 = 0.f, d2 = 0.f, dl = 0.f;

#pragma unroll
  for (int q = 0; q < 2; ++q) {
    int e8 = (lane + q * 64) * 8;
    f16x8 a0 = *(const f16x8*)(h0 + e8);
    f16x8 a1 = *(const f16x8*)(h1 + e8);
    f16x8 a2 = *(const f16x8*)(h2 + e8);
    f16x8 al = *(const f16x8*)(lfr + e8);
    float4 u0a = *(const float4*)(wf + e8);
    float4 u0b = *(const float4*)(wf + e8 + 4);
    float4 u1a = *(const float4*)(wf + 1024 + e8);
    float4 u1b = *(const float4*)(wf + 1024 + e8 + 4);
    float wf0[8] = {u0a.x, u0a.y, u0a.z, u0a.w, u0b.x, u0b.y, u0b.z, u0b.w};
    float wf1[8] = {u1a.x, u1a.y, u1a.z, u1a.w, u1b.x, u1b.y, u1b.z, u1b.w};
#pragma unroll
    for (int j = 0; j < 8; ++j) {
      float p0 = (float)a0[j], p1 = (float)a1[j], p2 = (float)a2[j];
      float pl = (float)al[j];
      s01 = fmaf(p0, p1, s01);
      s02 = fmaf(p0, p2, s02);
      s12 = fmaf(p1, p2, s12);
      d0 = fmaf(p0, wf1[j], d0);
      d1 = fmaf(p1, wf1[j], d1);
      d2 = fmaf(p2, wf1[j], d2);
      dl = fmaf(pl, wf0[j], dl);
    }
  }

#pragma unroll
  for (int m = 1; m < 64; m <<= 1) {
    s01 += __shfl_xor(s01, m);
    s02 += __shfl_xor(s02, m);
    s12 += __shfl_xor(s12, m);
    d0 += __shfl_xor(d0, m);
    d1 += __shfl_xor(d1, m);
    d2 += __shfl_xor(d2, m);
    dl += __shfl_xor(dl, m);
  }

  if (lane == 0) {
    float c0 = 0.f, c1 = 0.f, c2 = 0.f;
    {
      float m = fmaxf(0.f, fmaxf(s01, s02));
      float e0 = expf(0.f - m), e1 = expf(s01 - m), e2 = expf(s02 - m);
      float inv = 1.f / (e0 + e1 + e2);
      c0 += e0 * inv; c1 += e1 * inv; c2 += e2 * inv;
    }
    {
      float m = fmaxf(s01, fmaxf(0.f, s12));
      float e0 = expf(s01 - m), e1 = expf(0.f - m), e2 = expf(s12 - m);
      float inv = 1.f / (e0 + e1 + e2);
      c0 += e0 * inv; c1 += e1 * inv; c2 += e2 * inv;
    }
    {
      float m = fmaxf(s02, fmaxf(s12, 0.f));
      float e0 = expf(s02 - m), e1 = expf(s12 - m), e2 = expf(0.f - m);
      float inv = 1.f / (e0 + e1 + e2);
      c0 += e0 * inv; c1 += e1 * inv; c2 += e2 * inv;
    }
    out[b] = dl + c0 * d0 + c1 * d1 + c2 * d2 + bfin[0];
  }
}

// ---------------------------------------------------------------------------
extern "C" void kernel_launch(void* const* d_in, const int* in_sizes, int n_in,
                              void* d_out, int out_size, void* d_ws,
                              size_t ws_size, hipStream_t stream) {
  const int* idx = (const int*)d_in[0];
  const float* emb = (const float*)d_in[1];
  const float* w0 = (const float*)d_in[2];
  const float* b0 = (const float*)d_in[3];
  const float* w1 = (const float*)d_in[4];
  const float* b1 = (const float*)d_in[5];
  const float* w2 = (const float*)d_in[6];
  const float* b2 = (const float*)d_in[7];
  const float* w3 = (const float*)d_in[8];
  const float* b3 = (const float*)d_in[9];
  const float* wf = (const float*)d_in[10];
  const float* bfin = (const float*)d_in[11];
  float* out = (float*)d_out;

  const size_t RB = (size_t)B_SZ * HID;  // 4M elements
  const size_t WSZ = (size_t)HID * HID;  // 1M elements

  _Float16* wt = (_Float16*)d_ws;   // [4][1024][1024]  8 MB
  _Float16* xw16 = wt + 4 * WSZ;    // [B,1024]         8 MB
  _Float16* cat16 = xw16 + RB;      // [3B,1024]       24 MB
  _Float16* lf16 = cat16 + 3 * RB;  // [B,1024]         8 MB

  prep<<<6144, 256, 0, stream>>>(idx, emb, w0, w1, w2, w3, wt, xw16);

  gemm_mfma<<<256, 512, 0, stream>>>(xw16, wt + 0 * WSZ, b0, cat16);
  gemm_mfma<<<256, 512, 0, stream>>>(cat16, wt + 1 * WSZ, b1, cat16 + RB);
  gemm_mfma<<<256, 512, 0, stream>>>(cat16 + RB, wt + 2 * WSZ, b2,
                                     cat16 + 2 * RB);
  gemm_mfma<<<256, 512, 0, stream>>>(cat16 + 2 * RB, wt + 3 * WSZ, b3, lf16);

  attn_final<<<B_SZ / 4, 256, 0, stream>>>(cat16, lf16, wf, bfin, out);
}

// Round 13
// 73.079 us; speedup vs baseline: 1.5786x; 1.0377x over previous
//
#include <hip/hip_runtime.h>
#include <hip/hip_bf16.h>
#include <stdint.h>

#define B_SZ 4096
#define F_N 16
#define V_SZ 20000
#define E_SZ 64
#define HID 1024

typedef __attribute__((ext_vector_type(8))) _Float16 f16x8;
typedef __attribute__((ext_vector_type(4))) _Float16 f16x4;
typedef __attribute__((ext_vector_type(4))) float f32x4;

__device__ __forceinline__ void gload16(const void* g, void* l) {
  __builtin_amdgcn_global_load_lds(
      (const __attribute__((address_space(1))) void*)g,
      (__attribute__((address_space(3))) void*)l, 16, 0, 0);
}

// s3(r): spreads a 128B-stride row-major LDS tile across the 8 16B bank
// groups (counter-verified r11: ~1 conflict-cycle per ds_read_b128, at the
// 2-lane/bank wave64 floor). s3(r+64) == s3(r).
__device__ __forceinline__ int s3(int r) { return (r ^ (r >> 3)) & 7; }

// ---------------------------------------------------------------------------
// prep: blocks [0,2048) convert+transpose weights (wt[z][n][k] = f16 w_z[k][n])
//       in 64k x 32n tiles with full-128B-line stores;
//       blocks [2048,6144) gather embeddings straight to f16.
// ---------------------------------------------------------------------------
__global__ __launch_bounds__(256) void prep(
    const int* __restrict__ idx, const float* __restrict__ emb,
    const float* __restrict__ w0, const float* __restrict__ w1,
    const float* __restrict__ w2, const float* __restrict__ w3,
    _Float16* __restrict__ wt, _Float16* __restrict__ xw) {
  const int cb = blockIdx.x;
  const int t = threadIdx.x;
  if (cb < 2048) {
    const int z = cb >> 9, rem = cb & 511;
    const float* w = (z == 0) ? w0 : (z == 1) ? w1 : (z == 2) ? w2 : w3;
    _Float16* outp = wt + (size_t)z * HID * HID;
    __shared__ float tile[64][33];
    const int k0 = (rem >> 5) * 64, n0 = (rem & 31) * 32;
    const int c = t & 31;
#pragma unroll
    for (int q = 0; q < 8; ++q) {
      int r = (t >> 5) + q * 8;  // k-row within tile
      tile[r][c] = w[(size_t)(k0 + r) * HID + n0 + c];
    }
    __syncthreads();
#pragma unroll
    for (int q = 0; q < 4; ++q) {
      int s = t + q * 256;  // 0..1023
      int n = s >> 5, c2 = s & 31;
      union { _Float16 h[2]; uint32_t u; } p;
      p.h[0] = (_Float16)tile[2 * c2][n];
      p.h[1] = (_Float16)tile[2 * c2 + 1][n];
      *(uint32_t*)(outp + (size_t)(n0 + n) * HID + k0 + 2 * c2) = p.u;
    }
  } else {
    int i = (cb - 2048) * 256 + t;  // f4 index in [0, B*256)
    int b = i >> 8;
    int r = i & 255;
    int f = r >> 4;
    int e4 = r & 15;
    int id = idx[b * F_N + f];
    float4 v = *(const float4*)(emb + ((size_t)f * V_SZ + id) * E_SZ + e4 * 4);
    f16x4 h = {(_Float16)v.x, (_Float16)v.y, (_Float16)v.z, (_Float16)v.w};
    *(f16x4*)(xw + (size_t)b * HID + r * 4) = h;
  }
}

// ---------------------------------------------------------------------------
// C = relu(A @ Wt^T + bias) -> f16.  MFMA 16x16x32_f16.
// r6 champion structure (73.2 us): 128x128 tile, BK=64, 8 waves split
// 2M x 2N x 2K (64x64 output quadrant, half-K per wave; (2,2) LDS read
// duplication). 2 LDS buffer pairs (64 KB), depth-1 prefetch via
// global_load_lds (pre-swizzled source chunk, linear dest, swizzled read),
// counted vmcnt, 2 raw barriers/iter. wk-pairs reduce partial accs through
// LDS once at the end (aliases the staging buffers).
// Structural floor: 96 KB LDS traffic/iter at ~85 B/cyc/CU > MFMA 621 cyc
// -> LDS-pipe-bound; r7 (1-barrier), r9 (frag-dbuf) schedule variants were
// neutral, B-in-registers (r5/r8), fusion (r11), co-resident converters
// (r10), swapped epilogue (r12) all regressed.
// XCD swizzle: XCD k (= bid%8) owns row-panels 4k..4k+3.
// ---------------------------------------------------------------------------
__global__ __launch_bounds__(512) void gemm_mfma(
    const _Float16* __restrict__ A, const _Float16* __restrict__ Wt,
    const float* __restrict__ bias, _Float16* __restrict__ C) {
  __shared__ __align__(16) _Float16 sh[2][2][128 * 64];
#define AS(b) (sh[b][0])
#define BS(b) (sh[b][1])

  const int t = threadIdx.x;
  const int l = ((blockIdx.x & 7) << 5) | (blockIdx.x >> 3);
  const int bm = (l >> 3) * 128, bn = (l & 7) * 128;

  const int w = t >> 6, lane = t & 63;
  const int wk = w & 1, wn = (w >> 1) & 1, wm = w >> 2;
  const int lr = lane & 15, lg = lane >> 4;

  // --- staging: slots s in [0,1024): row=s>>3, chunk=s&7 (16B units).
  // thread t owns slots {t, t+512} of each matrix; s3(srow)==s3(srow+64).
  const int srow = t >> 3, cdst = t & 7;
  const int csrc = cdst ^ s3(srow);
  const _Float16* ga0 = A + (size_t)(bm + srow) * HID + csrc * 8;
  const _Float16* gb0 = Wt + (size_t)(bn + srow) * HID + csrc * 8;
  const int ld0 = t * 8, ld1 = t * 8 + 4096;  // halves, linear dest

  // --- frag read offsets (halves): wave reads k-chunks wk*4+lg (k=wk*32..)
  int aoff[4], boff[4];
#pragma unroll
  for (int i = 0; i < 4; i++) {
    int ra = wm * 64 + i * 16 + lr;
    aoff[i] = ra * 64 + (((wk * 4 + lg) ^ s3(ra)) * 8);
    int rb = wn * 64 + i * 16 + lr;
    boff[i] = rb * 64 + (((wk * 4 + lg) ^ s3(rb)) * 8);
  }

  f32x4 acc[4][4] = {};

#define STAGE(buf, ko)                                   \
  gload16(ga0 + (ko), &AS(buf)[ld0]);                    \
  gload16(ga0 + (ko) + (size_t)64 * HID, &AS(buf)[ld1]); \
  gload16(gb0 + (ko), &BS(buf)[ld0]);                    \
  gload16(gb0 + (ko) + (size_t)64 * HID, &BS(buf)[ld1]);

  STAGE(0, 0)  // tile 0

  for (int tI = 0; tI < 16; ++tI) {
    const int cur = tI & 1;
    if (tI < 15) {
      STAGE(cur ^ 1, (tI + 1) * 64)  // prefetch next tile (4 loads/thread)
    }
    if (tI < 15)
      asm volatile("s_waitcnt vmcnt(4)" ::: "memory");  // tile tI landed
    else
      asm volatile("s_waitcnt vmcnt(0)" ::: "memory");
    asm volatile("s_barrier" ::: "memory");

    f16x8 a[4], b[4];
#pragma unroll
    for (int mi = 0; mi < 4; mi++) a[mi] = *(const f16x8*)&AS(cur)[aoff[mi]];
#pragma unroll
    for (int ni = 0; ni < 4; ni++) b[ni] = *(const f16x8*)&BS(cur)[boff[ni]];
#pragma unroll
    for (int mi = 0; mi < 4; mi++)
#pragma unroll
      for (int ni = 0; ni < 4; ni++)
        acc[mi][ni] = __builtin_amdgcn_mfma_f32_16x16x32_f16(
            a[mi], b[ni], acc[mi][ni], 0, 0, 0);

    asm volatile("s_barrier" ::: "memory");  // guard buffer overwrite
  }
#undef STAGE

  // --- wk-pair accumulator reduction through LDS (reuses sh, 64 KB).
  // addr = col*64 + (rb^(col&15))*4 (+j), rb=mi*4+lg; XOR keeps b128
  // writes/reads conflict-free.
  float* red = (float*)&sh[0][0][0];
  float* R = red + ((wm << 1) | wn) * 4096;
  if (wk == 1) {
#pragma unroll
    for (int mi = 0; mi < 4; mi++)
#pragma unroll
      for (int ni = 0; ni < 4; ni++) {
        int col = ni * 16 + lr;
        int rb = mi * 4 + lg;
        *(f32x4*)&R[col * 64 + ((rb ^ (col & 15)) << 2)] = acc[mi][ni];
      }
  }
  asm volatile("s_barrier" ::: "memory");
  if (wk == 0) {
#pragma unroll
    for (int mi = 0; mi < 4; mi++)
#pragma unroll
      for (int ni = 0; ni < 4; ni++) {
        int col = ni * 16 + lr;
        int rb = mi * 4 + lg;
        f32x4 p = *(const f32x4*)&R[col * 64 + ((rb ^ (col & 15)) << 2)];
        acc[mi][ni] += p;
      }
    // epilogue: D col = lane&15, row = (lane>>4)*4 + j
#pragma unroll
    for (int ni = 0; ni < 4; ni++) {
      int col = bn + wn * 64 + ni * 16 + lr;
      float bv = bias[col];
#pragma unroll
      for (int mi = 0; mi < 4; mi++) {
        int rbase = bm + wm * 64 + mi * 16 + lg * 4;
#pragma unroll
        for (int j = 0; j < 4; j++) {
          float x = acc[mi][ni][j] + bv;
          x = x > 0.f ? x : 0.f;
          C[(size_t)(rbase + j) * HID + col] = (_Float16)x;
        }
      }
    }
  }
#undef AS
#undef BS
}

// ---------------------------------------------------------------------------
// Attention-over-layers + final dot; reads f16 activations, fp32 math.
// Hm[b,j] = cat[3b+j] with cat = [l0; l1; l2] row-stacked.
// ---------------------------------------------------------------------------
__global__ __launch_bounds__(256) void attn_final(
    const _Float16* __restrict__ cat, const _Float16* __restrict__ lf,
    const float* __restrict__ wf, const float* __restrict__ bfin,
    float* __restrict__ out) {
  const int wave = threadIdx.x >> 6;
  const int lane = threadIdx.x & 63;
  const int b = blockIdx.x * 4 + wave;

  const _Float16* h0 = cat + (size_t)(3 * b + 0) * 1024;
  const _Float16* h1 = cat + (size_t)(3 * b + 1) * 1024;
  const _Float16* h2 = cat + (size_t)(3 * b + 2) * 1024;
  const _Float16* lfr = lf + (size_t)b * 1024;

  float s01 = 0.f, s02 = 0.f, s12 = 0.f;
  float d0 = 0.f, d1 = 0.f, d2 = 0.f, dl = 0.f;

#pragma unroll
  for (int q = 0; q < 2; ++q) {
    int e8 = (lane + q * 64) * 8;
    f16x8 a0 = *(const f16x8*)(h0 + e8);
    f16x8 a1 = *(const f16x8*)(h1 + e8);
    f16x8 a2 = *(const f16x8*)(h2 + e8);
    f16x8 al = *(const f16x8*)(lfr + e8);
    float4 u0a = *(const float4*)(wf + e8);
    float4 u0b = *(const float4*)(wf + e8 + 4);
    float4 u1a = *(const float4*)(wf + 1024 + e8);
    float4 u1b = *(const float4*)(wf + 1024 + e8 + 4);
    float wf0[8] = {u0a.x, u0a.y, u0a.z, u0a.w, u0b.x, u0b.y, u0b.z, u0b.w};
    float wf1[8] = {u1a.x, u1a.y, u1a.z, u1a.w, u1b.x, u1b.y, u1b.z, u1b.w};
#pragma unroll
    for (int j = 0; j < 8; ++j) {
      float p0 = (float)a0[j], p1 = (float)a1[j], p2 = (float)a2[j];
      float pl = (float)al[j];
      s01 = fmaf(p0, p1, s01);
      s02 = fmaf(p0, p2, s02);
      s12 = fmaf(p1, p2, s12);
      d0 = fmaf(p0, wf1[j], d0);
      d1 = fmaf(p1, wf1[j], d1);
      d2 = fmaf(p2, wf1[j], d2);
      dl = fmaf(pl, wf0[j], dl);
    }
  }

#pragma unroll
  for (int m = 1; m < 64; m <<= 1) {
    s01 += __shfl_xor(s01, m);
    s02 += __shfl_xor(s02, m);
    s12 += __shfl_xor(s12, m);
    d0 += __shfl_xor(d0, m);
    d1 += __shfl_xor(d1, m);
    d2 += __shfl_xor(d2, m);
    dl += __shfl_xor(dl, m);
  }

  if (lane == 0) {
    float c0 = 0.f, c1 = 0.f, c2 = 0.f;
    {
      float m = fmaxf(0.f, fmaxf(s01, s02));
      float e0 = expf(0.f - m), e1 = expf(s01 - m), e2 = expf(s02 - m);
      float inv = 1.f / (e0 + e1 + e2);
      c0 += e0 * inv; c1 += e1 * inv; c2 += e2 * inv;
    }
    {
      float m = fmaxf(s01, fmaxf(0.f, s12));
      float e0 = expf(s01 - m), e1 = expf(0.f - m), e2 = expf(s12 - m);
      float inv = 1.f / (e0 + e1 + e2);
      c0 += e0 * inv; c1 += e1 * inv; c2 += e2 * inv;
    }
    {
      float m = fmaxf(s02, fmaxf(s12, 0.f));
      float e0 = expf(s02 - m), e1 = expf(s12 - m), e2 = expf(0.f - m);
      float inv = 1.f / (e0 + e1 + e2);
      c0 += e0 * inv; c1 += e1 * inv; c2 += e2 * inv;
    }
    out[b] = dl + c0 * d0 + c1 * d1 + c2 * d2 + bfin[0];
  }
}

// ---------------------------------------------------------------------------
extern "C" void kernel_launch(void* const* d_in, const int* in_sizes, int n_in,
                              void* d_out, int out_size, void* d_ws,
                              size_t ws_size, hipStream_t stream) {
  const int* idx = (const int*)d_in[0];
  const float* emb = (const float*)d_in[1];
  const float* w0 = (const float*)d_in[2];
  const float* b0 = (const float*)d_in[3];
  const float* w1 = (const float*)d_in[4];
  const float* b1 = (const float*)d_in[5];
  const float* w2 = (const float*)d_in[6];
  const float* b2 = (const float*)d_in[7];
  const float* w3 = (const float*)d_in[8];
  const float* b3 = (const float*)d_in[9];
  const float* wf = (const float*)d_in[10];
  const float* bfin = (const float*)d_in[11];
  float* out = (float*)d_out;

  const size_t RB = (size_t)B_SZ * HID;  // 4M elements
  const size_t WSZ = (size_t)HID * HID;  // 1M elements

  _Float16* wt = (_Float16*)d_ws;   // [4][1024][1024]  8 MB
  _Float16* xw16 = wt + 4 * WSZ;    // [B,1024]         8 MB
  _Float16* cat16 = xw16 + RB;      // [3B,1024]       24 MB
  _Float16* lf16 = cat16 + 3 * RB;  // [B,1024]         8 MB

  prep<<<6144, 256, 0, stream>>>(idx, emb, w0, w1, w2, w3, wt, xw16);

  gemm_mfma<<<256, 512, 0, stream>>>(xw16, wt + 0 * WSZ, b0, cat16);
  gemm_mfma<<<256, 512, 0, stream>>>(cat16, wt + 1 * WSZ, b1, cat16 + RB);
  gemm_mfma<<<256, 512, 0, stream>>>(cat16 + RB, wt + 2 * WSZ, b2,
                                     cat16 + 2 * RB);
  gemm_mfma<<<256, 512, 0, stream>>>(cat16 + 2 * RB, wt + 3 * WSZ, b3, lf16);

  attn_final<<<B_SZ / 4, 256, 0, stream>>>(cat16, lf16, wf, bfin, out);
}